// Round 12
// baseline (447.696 us; speedup 1.0000x reference)
//
#include <hip/hip_runtime.h>
#include <hip/hip_bf16.h>
#include <hip/hip_cooperative_groups.h>

#define N_NODES 25000
#define N_EDGES 320000
#define F 64
#define H 5
#define R 20
#define B 10
#define HF 320            // H*F
#define MPAD 25008        // 1563*16 rows

typedef __attribute__((ext_vector_type(8))) short short8;
typedef __attribute__((ext_vector_type(4))) short short4v;
typedef __attribute__((ext_vector_type(4))) float float4v;

__device__ __forceinline__ float ldf(const void* p, int f32, int i) {
    if (f32) return ((const float*)p)[i];
    else     return __bfloat162float(((const __hip_bfloat16*)p)[i]);
}
__device__ __forceinline__ int ldi(const void* p, int i64, int i) {
    if (i64) return ((const int*)p)[2 * i];
    else     return ((const int*)p)[i];
}
__device__ __forceinline__ float b2f(unsigned short u) {
    union { unsigned u32; float f; } v; v.u32 = ((unsigned)u) << 16; return v.f;
}
__device__ __forceinline__ short f2bs(float x) {
    __hip_bfloat16 v = __float2bfloat16(x); return *(short*)&v;
}

// ---- inline dtype probes (wave-uniform)
__device__ __forceinline__ int probe_f32(const void* feat_raw) {
    unsigned w = ((const unsigned*)feat_raw)[threadIdx.x & 63];
    unsigned e = (w >> 7) & 0xFF;
    unsigned long long m = __ballot(e >= 110 && e <= 140);
    return __popcll(m) < 32;
}
__device__ __forceinline__ int probe_i64(const void* src_raw) {
    unsigned v = ((const unsigned*)src_raw)[2 * (threadIdx.x & 63) + 1];
    unsigned long long m = __ballot(v == 0);
    return __popcll(m) > 32;
}

// ---------------- K1: blocks 0..175 pack weights; blocks 176.. hist + featb cvt
__global__ void k1_setup(const void* __restrict__ feat, const void* __restrict__ src,
                         const void* __restrict__ fcw, const void* __restrict__ sfw,
                         const void* __restrict__ aw, const void* __restrict__ wc,
                         const void* __restrict__ dst,
                         __hip_bfloat16* __restrict__ Wpack,
                         __hip_bfloat16* __restrict__ W2pack,
                         __hip_bfloat16* __restrict__ featb,
                         int* __restrict__ deg) {
    const int f32 = probe_f32(feat);
    const int i64 = probe_i64(src);
    const int b = blockIdx.x, tid = threadIdx.x;
    if (b < 176) {
        const int idx = b * 256 + tid;
        if (idx < 24576) {
            int j = idx & 7, lane = (idx >> 3) & 63, fq = idx >> 9;
            int q = fq & 1, t = fq >> 1;
            int k = (q ? 32 : 0) + ((lane >> 4) << 3) + j;
            int c = t * 16 + (lane & 15);
            float v = (c < HF) ? ldf(sfw, f32, k * HF + c) : ldf(fcw, f32, k * F + (c - HF));
            Wpack[idx] = __float2bfloat16(v);
        } else if (idx < 24576 + 20480) {
            int id2 = idx - 24576;
            int j = id2 & 7, lane = (id2 >> 3) & 63, fq = id2 >> 9;
            int q = fq & 1, t = fq >> 1;
            int k = (q ? 32 : 0) + ((lane >> 4) << 3) + j;
            int c = t * 16 + (lane & 15);
            int r = c >> 4, part = (c >> 3) & 1, h = c & 7;
            float acc = 0.f;
            if (h < H) {
#pragma unroll
                for (int bb = 0; bb < B; ++bb)
                    acc += ldf(wc, f32, r * B + bb) *
                           ldf(aw, f32, bb * (2 * F * H) + (part * F + k) * H + h);
            }
            W2pack[id2] = __float2bfloat16(acc);
        }
    } else {
        const int e = (b - 176) * 256 + tid;
        if (e < N_EDGES) atomicAdd(&deg[ldi(dst, i64, e)], 1);
        if (f32) {
            for (int i = e; i < N_NODES * F; i += 1250 * 256)
                featb[i] = __float2bfloat16(((const float*)feat)[i]);
        }
    }
}

// ---------------- K2: fused GEMM1+GEMM2, transposed epilogues (packed 8B stores)
__global__ __launch_bounds__(256) void k2_gemm(const void* __restrict__ feat,
                                               const __hip_bfloat16* __restrict__ featb,
                                               const __hip_bfloat16* __restrict__ Wpack,
                                               const __hip_bfloat16* __restrict__ W2pack,
                                               __hip_bfloat16* __restrict__ selfz,
                                               __hip_bfloat16* __restrict__ zc,
                                               __hip_bfloat16* __restrict__ a_src,
                                               __hip_bfloat16* __restrict__ a_dst) {
    __shared__ short zl[16][68];   // 68: 8B-aligned rows, conflict-free stride
    const int f32 = probe_f32(feat);
    const __hip_bfloat16* A = f32 ? featb : (const __hip_bfloat16*)feat;
    const int tid = threadIdx.x;
    const int wave = tid >> 6, lane = tid & 63;
    const int quad = lane >> 4, col = lane & 15;
    const int r0 = blockIdx.x * 16;
    int am = r0 + col;
    if (am >= N_NODES) am = N_NODES - 1;
    const int row = r0 + col;

    short8 a0 = *(const short8*)(A + am * F + quad * 8);
    short8 a1 = *(const short8*)(A + am * F + 32 + quad * 8);

    const short8* Wp = (const short8*)Wpack;

    // ---- zc tile (t = 20 + wave): global + LDS stage, packed stores
    {
        const int t = 20 + wave;
        short8 b0 = Wp[(t * 2 + 0) * 64 + lane];
        short8 b1 = Wp[(t * 2 + 1) * 64 + lane];
        float4v acc = {0.f, 0.f, 0.f, 0.f};
        acc = __builtin_amdgcn_mfma_f32_16x16x32_bf16(b0, a0, acc, 0, 0, 0);
        acc = __builtin_amdgcn_mfma_f32_16x16x32_bf16(b1, a1, acc, 0, 0, 0);
        short4v pv;
#pragma unroll
        for (int j = 0; j < 4; ++j) pv[j] = f2bs(acc[j]);
        const int cb = wave * 16 + quad * 4;
        *(short4v*)(zc + row * F + cb) = pv;
        *(short4v*)&zl[col][cb] = pv;
    }
    __syncthreads();

    short8 c0 = *(const short8*)&zl[col][quad * 8];
    short8 c1 = *(const short8*)&zl[col][32 + quad * 8];

    // ---- selfz tiles (t = wave*5 .. +4)
#pragma unroll
    for (int tt = 0; tt < 5; ++tt) {
        const int t = wave * 5 + tt;
        short8 b0 = Wp[(t * 2 + 0) * 64 + lane];
        short8 b1 = Wp[(t * 2 + 1) * 64 + lane];
        float4v acc = {0.f, 0.f, 0.f, 0.f};
        acc = __builtin_amdgcn_mfma_f32_16x16x32_bf16(b0, a0, acc, 0, 0, 0);
        acc = __builtin_amdgcn_mfma_f32_16x16x32_bf16(b1, a1, acc, 0, 0, 0);
        short4v pv;
#pragma unroll
        for (int j = 0; j < 4; ++j) pv[j] = f2bs(acc[j]);
        *(short4v*)(selfz + row * HF + t * 16 + quad * 4) = pv;
    }

    // ---- GEMM2 tiles -> a_src (quads 0,1) / a_dst (quads 2,3)
    const short8* W2p = (const short8*)W2pack;
    __hip_bfloat16* dsta = (quad & 2) ? a_dst : a_src;
    const int hoff = (quad & 1) * 4;
#pragma unroll
    for (int tt = 0; tt < 5; ++tt) {
        const int t = wave * 5 + tt;
        short8 b0 = W2p[(t * 2 + 0) * 64 + lane];
        short8 b1 = W2p[(t * 2 + 1) * 64 + lane];
        float4v acc = {0.f, 0.f, 0.f, 0.f};
        acc = __builtin_amdgcn_mfma_f32_16x16x32_bf16(b0, c0, acc, 0, 0, 0);
        acc = __builtin_amdgcn_mfma_f32_16x16x32_bf16(b1, c1, acc, 0, 0, 0);
        short4v pv;
#pragma unroll
        for (int j = 0; j < 4; ++j) pv[j] = f2bs(acc[j]);
        *(short4v*)(dsta + row * 160 + t * 8 + hoff) = pv;
    }
}

// ---------------- K_SC: cooperative scan + scatter (1024 blocks x 256)
__global__ __launch_bounds__(256) void k_sc(const void* __restrict__ src,
                                            const void* __restrict__ dst,
                                            const void* __restrict__ et,
                                            const int* __restrict__ deg,
                                            int* __restrict__ rowptr,
                                            int* __restrict__ cursor,
                                            unsigned* __restrict__ perm,
                                            int* __restrict__ blockTot) {
    const int b = blockIdx.x, tid = threadIdx.x;
    const int i64 = probe_i64(src);
    __shared__ int sloc[25];
    const int nidx = b * 25 + tid;
    if (tid < 25) sloc[tid] = (nidx < N_NODES) ? deg[nidx] : 0;
    __syncthreads();
    if (tid == 0) {
        int run = 0;
#pragma unroll
        for (int j = 0; j < 25; ++j) { int v = sloc[j]; sloc[j] = run; run += v; }
        blockTot[b] = run;
    }
    cooperative_groups::this_grid().sync();

    if (b == 0) {                      // scan the 1024 block totals
        __shared__ int stot[1024];
        __shared__ int chunk[256];
        for (int j = tid; j < 1024; j += 256) stot[j] = blockTot[j];
        __syncthreads();
        int s = stot[tid * 4] + stot[tid * 4 + 1] + stot[tid * 4 + 2] + stot[tid * 4 + 3];
        chunk[tid] = s;
        __syncthreads();
        for (int off = 1; off < 256; off <<= 1) {
            int v = (tid >= off) ? chunk[tid - off] : 0;
            __syncthreads();
            chunk[tid] += v;
            __syncthreads();
        }
        int run = (tid > 0) ? chunk[tid - 1] : 0;
#pragma unroll
        for (int j = 0; j < 4; ++j) { int v = stot[tid * 4 + j]; stot[tid * 4 + j] = run; run += v; }
        __syncthreads();
        for (int j = tid; j < 1024; j += 256) blockTot[j] = stot[j];
        if (tid == 255) rowptr[N_NODES] = chunk[255];
    }
    cooperative_groups::this_grid().sync();

    if (tid < 25 && nidx < N_NODES) {
        int v = blockTot[b] + sloc[tid];
        rowptr[nidx] = v;
        cursor[nidx] = v;
    }
    cooperative_groups::this_grid().sync();

    for (int e = b * 256 + tid; e < N_EDGES; e += 1024 * 256) {
        int d = ldi(dst, i64, e);
        int s = ldi(src, i64, e);
        int r = ldi(et, i64, e);
        int pos = atomicAdd(&cursor[d], 1);
        perm[pos] = ((unsigned)r << 16) | (unsigned)s;
    }
}

// ---------------- K4: one wave per dst — 4-deep unrolled gather + aggregate
__global__ __launch_bounds__(256) void k4_agg(const void* __restrict__ feat_raw,
                                              const __hip_bfloat16* __restrict__ selfz,
                                              const unsigned short* __restrict__ zc,
                                              const __hip_bfloat16* __restrict__ a_src,
                                              const __hip_bfloat16* __restrict__ a_dst,
                                              const int* __restrict__ rowptr,
                                              const unsigned* __restrict__ perm,
                                              void* __restrict__ out) {
    __shared__ short sdv[4][160];
    const int f32 = probe_f32(feat_raw);
    const int tid = threadIdx.x;
    const int wid = tid >> 6, lane = tid & 63;
    const int d = blockIdx.x * 4 + wid;       // 6250*4 = 25000

    if (lane < 20)
        *(short8*)&sdv[wid][lane * 8] = *(const short8*)((const short*)a_dst + d * 160 + lane * 8);
    __syncthreads();

    const int beg = rowptr[d], end = rowptr[d + 1];
    const short* as = (const short*)a_src;

    float acc[H] = {0.f, 0.f, 0.f, 0.f, 0.f};
    int e = beg;
    for (; e + 4 <= end; e += 4) {
        unsigned pk[4];
        int s_[4], r_[4];
#pragma unroll
        for (int u = 0; u < 4; ++u) pk[u] = perm[e + u];
#pragma unroll
        for (int u = 0; u < 4; ++u) { s_[u] = (int)(pk[u] & 0xFFFFu); r_[u] = (int)(pk[u] >> 16); }
        short8 sv[4];
        float zs[4];
#pragma unroll
        for (int u = 0; u < 4; ++u) sv[u] = *(const short8*)(as + s_[u] * 160 + r_[u] * 8);
#pragma unroll
        for (int u = 0; u < 4; ++u) zs[u] = b2f(zc[s_[u] * F + lane]);
        short8 dv[4];
#pragma unroll
        for (int u = 0; u < 4; ++u) dv[u] = *(const short8*)&sdv[wid][r_[u] * 8];
#pragma unroll
        for (int u = 0; u < 4; ++u) {
#pragma unroll
            for (int h = 0; h < H; ++h) {
                float t = b2f((unsigned short)sv[u][h]) + b2f((unsigned short)dv[u][h]);
                acc[h] += fmaxf(t, 0.01f * t) * zs[u];
            }
        }
    }
    for (; e < end; ++e) {
        const unsigned pk = perm[e];
        const int s = (int)(pk & 0xFFFFu), r = (int)(pk >> 16);
        short8 sv = *(const short8*)(as + s * 160 + r * 8);
        const float zs = b2f(zc[s * F + lane]);
        short8 dv = *(const short8*)&sdv[wid][r * 8];
#pragma unroll
        for (int h = 0; h < H; ++h) {
            float t = b2f((unsigned short)sv[h]) + b2f((unsigned short)dv[h]);
            acc[h] += fmaxf(t, 0.01f * t) * zs;
        }
    }

    const int ob = d * HF + lane;
    if (f32) {
        float* o = (float*)out;
#pragma unroll
        for (int h = 0; h < H; ++h)
            o[ob + h * F] = acc[h] + __bfloat162float(selfz[ob + h * F]);
    } else {
        __hip_bfloat16* o = (__hip_bfloat16*)out;
#pragma unroll
        for (int h = 0; h < H; ++h)
            o[ob + h * F] = __float2bfloat16(acc[h] + __bfloat162float(selfz[ob + h * F]));
    }
}

extern "C" void kernel_launch(void* const* d_in, const int* in_sizes, int n_in,
                              void* d_out, int out_size, void* d_ws, size_t ws_size,
                              hipStream_t stream) {
    const void* feat = d_in[0];
    const void* src  = d_in[1];
    const void* dst  = d_in[2];
    const void* et   = d_in[3];
    const void* fcw  = d_in[4];
    const void* sfw  = d_in[5];
    const void* aw   = d_in[6];
    const void* wc   = d_in[7];

    char* w = (char*)d_ws;
    __hip_bfloat16* selfz  = (__hip_bfloat16*)w;  w += (size_t)MPAD * HF * 2;
    __hip_bfloat16* zc     = (__hip_bfloat16*)w;  w += (size_t)MPAD * F * 2;
    __hip_bfloat16* a_src  = (__hip_bfloat16*)w;  w += (size_t)MPAD * 160 * 2;
    __hip_bfloat16* a_dst  = (__hip_bfloat16*)w;  w += (size_t)MPAD * 160 * 2;
    __hip_bfloat16* featb  = (__hip_bfloat16*)w;  w += (size_t)N_NODES * F * 2;
    __hip_bfloat16* Wpack  = (__hip_bfloat16*)w;  w += 24576 * 2;
    __hip_bfloat16* W2pack = (__hip_bfloat16*)w;  w += 20480 * 2;
    unsigned* perm = (unsigned*)w;                w += (size_t)N_EDGES * 4;
    int* deg       = (int*)w;                     w += (size_t)N_NODES * 4;
    int* cursor    = (int*)w;                     w += (size_t)N_NODES * 4;
    int* rowptr    = (int*)w;                     w += (size_t)(N_NODES + 1) * 4;
    int* blockTot  = (int*)w;

    hipMemsetAsync(deg, 0, (size_t)N_NODES * 4, stream);
    k1_setup<<<176 + 1250, 256, 0, stream>>>(feat, src, fcw, sfw, aw, wc, dst,
                                             Wpack, W2pack, featb, deg);
    k2_gemm<<<1563, 256, 0, stream>>>(feat, featb, Wpack, W2pack, selfz, zc, a_src, a_dst);

    void* args[] = {(void*)&src, (void*)&dst, (void*)&et, (void*)&deg, (void*)&rowptr,
                    (void*)&cursor, (void*)&perm, (void*)&blockTot};
    hipLaunchCooperativeKernel((void*)k_sc, dim3(1024), dim3(256), args, 0, stream);

    k4_agg<<<N_NODES / 4, 256, 0, stream>>>(feat, selfz, (const unsigned short*)zc,
                                            a_src, a_dst, rowptr, perm, d_out);
}